// Round 13
// baseline (108.328 us; speedup 1.0000x reference)
//
#include <hip/hip_runtime.h>

// Chamfer loss: x [B,N,D], y [B,M,D], D=3, fp32.
// dist[b,m,n] = ||x[b,n]-y[b,m]||^2
// row[b] = mean_n min_m dist ; col[b] = mean_m min_n dist
// out = mean_b max(row, col)
//
// R13: INSTRUMENTATION ROUND. R11 (best measured, 84.2 us) with the hot
// target-scan loop repeated REPEAT=3x. Min-scan over the same target set is
// idempotent -> result identical; a memory barrier between reps stops the
// compiler from collapsing them. K1 triples (~60-90 us) so it finally beats
// the harness's ~44 us poison fills into rocprof's top-5 and we read its
// VALUBusy / Occupancy / LDS_BANK_CONFLICT / VGPR for the first time since
// R3. Marginal cost (total - 84.2)/2 = true per-pass hot-loop time.

#define BATCH   32
#define NPTS    2048
#define THREADS 128
#define QPT     16             // 128*16 = 2048 x-queries per block
#define TCH     64             // y-chunks per batch
#define TC      (NPTS / TCH)   // 32 y-targets per chunk
#define NROWB   (BATCH * 8)    // 256 row-combine blocks
#define NCOLB   BATCH          // 32 col-sum blocks
#define REPEAT  3              // diagnostic repetition of the hot loop

__global__ __launch_bounds__(THREADS, 4) void chamfer_min(
    const float* __restrict__ x, const float* __restrict__ y,
    float* __restrict__ part    /* [BATCH][TCH][NPTS] */,
    float* __restrict__ colmin  /* [BATCH][NPTS] */)
{
    __shared__ float4 t4[TC];                 // (ty0,ty1,ty2, h_y) — 512 B
    __shared__ float colLds[THREADS][TC + 1]; // +1 pad — 16.9 KB
    __shared__ float cmPart[4][TC + 1];       // 528 B

    const int blk   = blockIdx.x;      // 2048
    const int b     = blk >> 6;
    const int chunk = blk & 63;

    const float* qp = x + (size_t)b * NPTS * 3;
    const float* tp = y + (size_t)b * NPTS * 3;

    // Stage this chunk's 32 y-targets with h_y = 0.5*||y||^2.
    if (threadIdx.x < TC) {
        int jj = chunk * TC + threadIdx.x;
        float ty0 = tp[3 * jj + 0];
        float ty1 = tp[3 * jj + 1];
        float ty2 = tp[3 * jj + 2];
        t4[threadIdx.x] = make_float4(ty0, ty1, ty2,
                                      0.5f * (ty0 * ty0 + ty1 * ty1 + ty2 * ty2));
    }

    // 16 x-queries per thread: negated coords + h_x.
    float nqx[QPT], nqy[QPT], nqz[QPT], hx[QPT], mn[QPT];
#pragma unroll
    for (int k = 0; k < QPT; ++k) {
        int qi = threadIdx.x + k * THREADS;
        float qx = qp[3 * qi + 0];
        float qy = qp[3 * qi + 1];
        float qz = qp[3 * qi + 2];
        nqx[k] = -qx;
        nqy[k] = -qy;
        nqz[k] = -qz;
        hx[k]  = 0.5f * (qx * qx + qy * qy + qz * qz);
        mn[k]  = 3.4e38f;
    }
    __syncthreads();

    // Hot loop, repeated REPEAT times (idempotent for min).
#pragma unroll 1
    for (int rep = 0; rep < REPEAT; ++rep) {
#pragma unroll 2
        for (int j = 0; j < TC; j += 2) {
            float4 a  = t4[j];                // wave-uniform -> broadcast
            float4 c4 = t4[j + 1];
            float colA = 3.4e38f, colB = 3.4e38f;
#pragma unroll
            for (int k = 0; k < QPT; k += 2) {
                float Wa0 = a.w  + hx[k],     Wb0 = c4.w + hx[k];
                float Wa1 = a.w  + hx[k + 1], Wb1 = c4.w + hx[k + 1];
                float s0 = fmaf(nqz[k], a.z, fmaf(nqy[k], a.y, fmaf(nqx[k], a.x, Wa0)));
                float s1 = fmaf(nqz[k], c4.z, fmaf(nqy[k], c4.y, fmaf(nqx[k], c4.x, Wb0)));
                float t0 = fmaf(nqz[k+1], a.z, fmaf(nqy[k+1], a.y, fmaf(nqx[k+1], a.x, Wa1)));
                float t1 = fmaf(nqz[k+1], c4.z, fmaf(nqy[k+1], c4.y, fmaf(nqx[k+1], c4.x, Wb1)));
                mn[k]     = fminf(fminf(mn[k], s0), s1);       // v_min3
                mn[k + 1] = fminf(fminf(mn[k + 1], t0), t1);   // v_min3
                colA = fminf(fminf(colA, s0), t0);             // v_min3
                colB = fminf(fminf(colB, s1), t1);             // v_min3
            }
            colLds[threadIdx.x][j]     = colA;
            colLds[threadIdx.x][j + 1] = colB;
        }
        // Pin the repetition: forbid hoisting/merging across reps.
        asm volatile("" ::: "memory");
    }
    __syncthreads();

    // Col reduce: 4 groups of 32 rows, one (group, target) per thread.
    {
        const int g = threadIdx.x >> 5;    // 0..3
        const int j = threadIdx.x & 31;    // target within chunk
        float cp = 3.4e38f;
#pragma unroll
        for (int i = 0; i < 32; ++i)
            cp = fminf(cp, colLds[g * 32 + i][j]);
        cmPart[g][j] = cp;
    }
    __syncthreads();
    if (threadIdx.x < TC) {
        const int j = threadIdx.x;
        float cm = fminf(fminf(cmPart[0][j], cmPart[1][j]),
                         fminf(cmPart[2][j], cmPart[3][j]));
        colmin[(size_t)b * NPTS + chunk * TC + j] = cm;   // complete col-min
    }

    // Row partials: plain coalesced writes — no init, no atomics.
    float* pbase = part + ((size_t)b * TCH + chunk) * NPTS;
#pragma unroll
    for (int k = 0; k < QPT; ++k)
        pbase[threadIdx.x + k * THREADS] = mn[k];
}

#define CTHREADS 256

__global__ __launch_bounds__(CTHREADS) void chamfer_combine(
    const float* __restrict__ part,
    const float* __restrict__ colmin,
    float* __restrict__ blocksums /* [NROWB + NCOLB] */)
{
    __shared__ float wsum[CTHREADS / 64];

    const int blk = blockIdx.x;        // 288 = NROWB + NCOLB
    float d;

    if (blk < NROWB) {
        // Row: min over 64 chunks for one query, d = 2c.
        const int b  = blk >> 3;
        const int qc = blk & 7;
        const int qi = qc * CTHREADS + threadIdx.x;
        const float* p = part + (size_t)b * TCH * NPTS + qi;
        float mn = p[0];
#pragma unroll
        for (int c = 1; c < TCH; ++c)
            mn = fminf(mn, p[(size_t)c * NPTS]);
        d = 2.0f * mn;
    } else {
        // Col: sum 2*colmin over this batch (8 values per thread).
        const int b = blk - NROWB;
        const float* p = colmin + (size_t)b * NPTS;
        float s = 0.0f;
#pragma unroll
        for (int i = 0; i < 8; ++i)
            s += p[threadIdx.x + i * CTHREADS];
        d = 2.0f * s;
    }

    for (int off = 32; off > 0; off >>= 1)
        d += __shfl_down(d, off);
    if ((threadIdx.x & 63) == 0) wsum[threadIdx.x >> 6] = d;
    __syncthreads();
    if (threadIdx.x == 0)
        blocksums[blk] = wsum[0] + wsum[1] + wsum[2] + wsum[3];
}

__global__ void chamfer_finalize(const float* __restrict__ blocksums,
                                 float* __restrict__ out)
{
    const int lane = threadIdx.x;   // 64 threads; lanes >= 32 contribute 0
    float v = 0.0f;
    if (lane < BATCH) {
        float rs = 0.0f;
#pragma unroll
        for (int i = 0; i < 8; ++i)
            rs += blocksums[lane * 8 + i];
        float cs = blocksums[NROWB + lane];
        v = fmaxf(rs, cs) * (1.0f / NPTS);
    }
    for (int off = 32; off > 0; off >>= 1)
        v += __shfl_down(v, off);
    if (lane == 0) out[0] = v * (1.0f / BATCH);
}

extern "C" void kernel_launch(void* const* d_in, const int* in_sizes, int n_in,
                              void* d_out, int out_size, void* d_ws, size_t ws_size,
                              hipStream_t stream) {
    const float* x = (const float*)d_in[0];
    const float* y = (const float*)d_in[1];
    float* out = (float*)d_out;

    float* part      = (float*)d_ws;                          // 16 MB
    float* colmin    = part + (size_t)BATCH * TCH * NPTS;     // 256 KB
    float* blocksums = colmin + (size_t)BATCH * NPTS;         // ~1.2 KB

    chamfer_min<<<BATCH * TCH, THREADS, 0, stream>>>(x, y, part, colmin);
    chamfer_combine<<<NROWB + NCOLB, CTHREADS, 0, stream>>>(part, colmin, blocksums);
    chamfer_finalize<<<1, 64, 0, stream>>>(blocksums, out);
}

// Round 14
// 78.641 us; speedup vs baseline: 1.3775x; 1.3775x over previous
//
#include <hip/hip_runtime.h>

// Chamfer loss: x [B,N,D], y [B,M,D], D=3, fp32.
// dist[b,m,n] = ||x[b,n]-y[b,m]||^2
// row[b] = mean_n min_m dist ; col[b] = mean_m min_n dist
// out = mean_b max(row, col)
//
// R14: R13 found K1 is VALU-issue-bound end-to-end (VALUBusy~100%, 0 bank
// conflicts) with hot loop at its 12 us floor but ~17 us of per-K1 overhead
// (prologue x2048 blocks + col epilogue + ramp) and K2 reading 16 MB.
// -> amortize: 512 blocks x 256 thr scan 128 targets each (4 col-groups of
// 32), prologue count /4, part array 16->4 MB, same hot-loop instr total.
//  K1: 512 blocks (32 b x 16 tchunks) x 256 thr, QPT=8 (all 2048 queries).
//      c(n,m) = h_x + h_y - x.y (dist=2c, computed ONCE, serves both dirs).
//      Row partials -> part[b][chunk][n]; complete col-mins -> colmin[b][m]
//      via padded-LDS tree per 32-target group.
//  K2: 256 row blocks (min over 16 chunks) + 32 col blocks -> blocksums.
//  K3: 1 block x 64: per-batch means -> max(row,col) -> mean -> out.

#define BATCH   32
#define NPTS    2048
#define THREADS 256
#define QPT     8              // 256*8 = 2048 x-queries per block
#define TCH     16             // y-chunks per batch
#define TC      (NPTS / TCH)   // 128 y-targets per chunk
#define GRP     32             // targets per col-reduce group
#define NGRP    (TC / GRP)     // 4 groups
#define NROWB   (BATCH * 8)    // 256 row-combine blocks
#define NCOLB   BATCH          // 32 col-sum blocks

__global__ __launch_bounds__(THREADS) void chamfer_min(
    const float* __restrict__ x, const float* __restrict__ y,
    float* __restrict__ part    /* [BATCH][TCH][NPTS] */,
    float* __restrict__ colmin  /* [BATCH][NPTS] */)
{
    __shared__ float4 t4[TC];                  // 128 targets — 2 KB
    __shared__ float colLds[THREADS][GRP + 1]; // 33.8 KB, stride 33: conflict-free
    __shared__ float cmPart[8][GRP + 1];       // 1 KB

    const int blk   = blockIdx.x;      // 512
    const int b     = blk >> 4;
    const int chunk = blk & 15;

    const float* qp = x + (size_t)b * NPTS * 3;
    const float* tp = y + (size_t)b * NPTS * 3;

    // Stage this chunk's 128 y-targets with h_y = 0.5*||y||^2.
    if (threadIdx.x < TC) {
        int jj = chunk * TC + threadIdx.x;
        float ty0 = tp[3 * jj + 0];
        float ty1 = tp[3 * jj + 1];
        float ty2 = tp[3 * jj + 2];
        t4[threadIdx.x] = make_float4(ty0, ty1, ty2,
                                      0.5f * (ty0 * ty0 + ty1 * ty1 + ty2 * ty2));
    }

    // 8 x-queries per thread: negated coords + h_x.
    float nqx[QPT], nqy[QPT], nqz[QPT], hx[QPT], mn[QPT];
#pragma unroll
    for (int k = 0; k < QPT; ++k) {
        int qi = threadIdx.x + k * THREADS;
        float qx = qp[3 * qi + 0];
        float qy = qp[3 * qi + 1];
        float qz = qp[3 * qi + 2];
        nqx[k] = -qx;
        nqy[k] = -qy;
        nqz[k] = -qz;
        hx[k]  = 0.5f * (qx * qx + qy * qy + qz * qz);
        mn[k]  = 3.4e38f;
    }
    __syncthreads();

    // 4 groups of 32 targets: hot scan + col tree-reduce per group.
#pragma unroll 1
    for (int g = 0; g < NGRP; ++g) {
        const float4* tg = &t4[g * GRP];
#pragma unroll 2
        for (int j = 0; j < GRP; j += 2) {
            float4 a  = tg[j];                // wave-uniform -> broadcast
            float4 c4 = tg[j + 1];
            float colA = 3.4e38f, colB = 3.4e38f;
#pragma unroll
            for (int k = 0; k < QPT; k += 2) {
                float Wa0 = a.w  + hx[k],     Wb0 = c4.w + hx[k];
                float Wa1 = a.w  + hx[k + 1], Wb1 = c4.w + hx[k + 1];
                float s0 = fmaf(nqz[k], a.z, fmaf(nqy[k], a.y, fmaf(nqx[k], a.x, Wa0)));
                float s1 = fmaf(nqz[k], c4.z, fmaf(nqy[k], c4.y, fmaf(nqx[k], c4.x, Wb0)));
                float t0 = fmaf(nqz[k+1], a.z, fmaf(nqy[k+1], a.y, fmaf(nqx[k+1], a.x, Wa1)));
                float t1 = fmaf(nqz[k+1], c4.z, fmaf(nqy[k+1], c4.y, fmaf(nqx[k+1], c4.x, Wb1)));
                mn[k]     = fminf(fminf(mn[k], s0), s1);       // v_min3
                mn[k + 1] = fminf(fminf(mn[k + 1], t0), t1);   // v_min3
                colA = fminf(fminf(colA, s0), t0);             // v_min3
                colB = fminf(fminf(colB, s1), t1);             // v_min3
            }
            colLds[threadIdx.x][j]     = colA;
            colLds[threadIdx.x][j + 1] = colB;
        }
        __syncthreads();

        // Col tree: 8 row-groups of 32 threads, one (rowgroup, target)/thread.
        {
            const int rg = threadIdx.x >> 5;   // 0..7
            const int t  = threadIdx.x & 31;   // target within group
            float cp = 3.4e38f;
#pragma unroll
            for (int i = 0; i < 32; ++i)
                cp = fminf(cp, colLds[rg * 32 + i][t]);
            cmPart[rg][t] = cp;
        }
        __syncthreads();
        if (threadIdx.x < GRP) {
            const int t = threadIdx.x;
            float cm = fminf(
                fminf(fminf(cmPart[0][t], cmPart[1][t]), fminf(cmPart[2][t], cmPart[3][t])),
                fminf(fminf(cmPart[4][t], cmPart[5][t]), fminf(cmPart[6][t], cmPart[7][t])));
            colmin[(size_t)b * NPTS + chunk * TC + g * GRP + t] = cm;
        }
        __syncthreads();
    }

    // Row partials: plain coalesced writes — no init, no atomics.
    float* pbase = part + ((size_t)b * TCH + chunk) * NPTS;
#pragma unroll
    for (int k = 0; k < QPT; ++k)
        pbase[threadIdx.x + k * THREADS] = mn[k];
}

#define CTHREADS 256

__global__ __launch_bounds__(CTHREADS) void chamfer_combine(
    const float* __restrict__ part,
    const float* __restrict__ colmin,
    float* __restrict__ blocksums /* [NROWB + NCOLB] */)
{
    __shared__ float wsum[CTHREADS / 64];

    const int blk = blockIdx.x;        // 288 = NROWB + NCOLB
    float d;

    if (blk < NROWB) {
        // Row: min over 16 chunks for one query, d = 2c.
        const int b  = blk >> 3;
        const int qc = blk & 7;
        const int qi = qc * CTHREADS + threadIdx.x;
        const float* p = part + (size_t)b * TCH * NPTS + qi;
        float mn = p[0];
#pragma unroll
        for (int c = 1; c < TCH; ++c)
            mn = fminf(mn, p[(size_t)c * NPTS]);
        d = 2.0f * mn;
    } else {
        // Col: sum 2*colmin over this batch (8 values per thread).
        const int b = blk - NROWB;
        const float* p = colmin + (size_t)b * NPTS;
        float s = 0.0f;
#pragma unroll
        for (int i = 0; i < 8; ++i)
            s += p[threadIdx.x + i * CTHREADS];
        d = 2.0f * s;
    }

    for (int off = 32; off > 0; off >>= 1)
        d += __shfl_down(d, off);
    if ((threadIdx.x & 63) == 0) wsum[threadIdx.x >> 6] = d;
    __syncthreads();
    if (threadIdx.x == 0)
        blocksums[blk] = wsum[0] + wsum[1] + wsum[2] + wsum[3];
}

__global__ void chamfer_finalize(const float* __restrict__ blocksums,
                                 float* __restrict__ out)
{
    const int lane = threadIdx.x;   // 64 threads; lanes >= 32 contribute 0
    float v = 0.0f;
    if (lane < BATCH) {
        float rs = 0.0f;
#pragma unroll
        for (int i = 0; i < 8; ++i)
            rs += blocksums[lane * 8 + i];
        float cs = blocksums[NROWB + lane];
        v = fmaxf(rs, cs) * (1.0f / NPTS);
    }
    for (int off = 32; off > 0; off >>= 1)
        v += __shfl_down(v, off);
    if (lane == 0) out[0] = v * (1.0f / BATCH);
}

extern "C" void kernel_launch(void* const* d_in, const int* in_sizes, int n_in,
                              void* d_out, int out_size, void* d_ws, size_t ws_size,
                              hipStream_t stream) {
    const float* x = (const float*)d_in[0];
    const float* y = (const float*)d_in[1];
    float* out = (float*)d_out;

    float* part      = (float*)d_ws;                          // 4 MB
    float* colmin    = part + (size_t)BATCH * TCH * NPTS;     // 256 KB
    float* blocksums = colmin + (size_t)BATCH * NPTS;         // ~1.2 KB

    chamfer_min<<<BATCH * TCH, THREADS, 0, stream>>>(x, y, part, colmin);
    chamfer_combine<<<NROWB + NCOLB, CTHREADS, 0, stream>>>(part, colmin, blocksums);
    chamfer_finalize<<<1, 64, 0, stream>>>(blocksums, out);
}

// Round 15
// 77.932 us; speedup vs baseline: 1.3900x; 1.0091x over previous
//
#include <hip/hip_runtime.h>

// Chamfer loss: x [B,N,D], y [B,M,D], D=3, fp32.
// dist[b,m,n] = ||x[b,n]-y[b,m]||^2
// row[b] = mean_n min_m dist ; col[b] = mean_m min_n dist
// out = mean_b max(row, col)
//
// R15: R13's smoking gun was VGPR_Count=56 for a QPT=16 kernel needing >=80
// floats of state: __launch_bounds__(128,4) capped the allocator, forcing
// reload-through-cache inside the hot loop (no scratch writes; L2 reloads
// invisible in FETCH). Fix: __launch_bounds__(128,1) -> ~110 VGPRs.
//  K1: 1024 blocks (32 b x 32 chunks) x 128 thr, QPT=16 (all 2048 queries
//      in regs), TC=64 targets staged in LDS, scanned in 2 groups of 32.
//      c(n,m) = h_x + h_y - x.y computed ONCE per pair, serves both dirs
//      (5 VALU instr / pair). Row partials -> part[b][chunk][n] (8 MB);
//      complete col-mins -> colmin[b][m] via padded-LDS tree per group.
//  K2: 256 row blocks (min over 32 chunks) + 32 col blocks -> blocksums.
//  K3: 1 block x 64: per-batch means -> max(row,col) -> mean -> out.

#define BATCH   32
#define NPTS    2048
#define THREADS 128
#define QPT     16             // 128*16 = 2048 x-queries per block
#define TCH     32             // y-chunks per batch
#define TC      (NPTS / TCH)   // 64 y-targets per chunk
#define GRP     32             // targets per col-reduce group
#define NGRP    (TC / GRP)     // 2 groups
#define NROWB   (BATCH * 8)    // 256 row-combine blocks
#define NCOLB   BATCH          // 32 col-sum blocks

__global__ __launch_bounds__(THREADS, 1) void chamfer_min(
    const float* __restrict__ x, const float* __restrict__ y,
    float* __restrict__ part    /* [BATCH][TCH][NPTS] */,
    float* __restrict__ colmin  /* [BATCH][NPTS] */)
{
    __shared__ float4 t4[TC];                  // 64 targets — 1 KB
    __shared__ float colLds[THREADS][GRP + 1]; // 16.9 KB, stride 33: conflict-free
    __shared__ float cmPart[4][GRP + 1];       // 528 B

    const int blk   = blockIdx.x;      // 1024
    const int b     = blk >> 5;
    const int chunk = blk & 31;

    const float* qp = x + (size_t)b * NPTS * 3;
    const float* tp = y + (size_t)b * NPTS * 3;

    // Stage this chunk's 64 y-targets with h_y = 0.5*||y||^2.
    if (threadIdx.x < TC) {
        int jj = chunk * TC + threadIdx.x;
        float ty0 = tp[3 * jj + 0];
        float ty1 = tp[3 * jj + 1];
        float ty2 = tp[3 * jj + 2];
        t4[threadIdx.x] = make_float4(ty0, ty1, ty2,
                                      0.5f * (ty0 * ty0 + ty1 * ty1 + ty2 * ty2));
    }

    // 16 x-queries per thread: negated coords + h_x. ~110 VGPRs — must NOT
    // be capped (that was R10-R13's hidden reload cost).
    float nqx[QPT], nqy[QPT], nqz[QPT], hx[QPT], mn[QPT];
#pragma unroll
    for (int k = 0; k < QPT; ++k) {
        int qi = threadIdx.x + k * THREADS;
        float qx = qp[3 * qi + 0];
        float qy = qp[3 * qi + 1];
        float qz = qp[3 * qi + 2];
        nqx[k] = -qx;
        nqy[k] = -qy;
        nqz[k] = -qz;
        hx[k]  = 0.5f * (qx * qx + qy * qy + qz * qz);
        mn[k]  = 3.4e38f;
    }
    __syncthreads();

    // 2 groups of 32 targets: hot scan + col tree-reduce per group.
#pragma unroll 1
    for (int g = 0; g < NGRP; ++g) {
        const float4* tg = &t4[g * GRP];
#pragma unroll 2
        for (int j = 0; j < GRP; j += 2) {
            float4 a  = tg[j];                // wave-uniform -> broadcast
            float4 c4 = tg[j + 1];
            float colA = 3.4e38f, colB = 3.4e38f;
#pragma unroll
            for (int k = 0; k < QPT; k += 2) {
                float Wa0 = a.w  + hx[k],     Wb0 = c4.w + hx[k];
                float Wa1 = a.w  + hx[k + 1], Wb1 = c4.w + hx[k + 1];
                float s0 = fmaf(nqz[k], a.z, fmaf(nqy[k], a.y, fmaf(nqx[k], a.x, Wa0)));
                float s1 = fmaf(nqz[k], c4.z, fmaf(nqy[k], c4.y, fmaf(nqx[k], c4.x, Wb0)));
                float t0 = fmaf(nqz[k+1], a.z, fmaf(nqy[k+1], a.y, fmaf(nqx[k+1], a.x, Wa1)));
                float t1 = fmaf(nqz[k+1], c4.z, fmaf(nqy[k+1], c4.y, fmaf(nqx[k+1], c4.x, Wb1)));
                mn[k]     = fminf(fminf(mn[k], s0), s1);       // v_min3
                mn[k + 1] = fminf(fminf(mn[k + 1], t0), t1);   // v_min3
                colA = fminf(fminf(colA, s0), t0);             // v_min3
                colB = fminf(fminf(colB, s1), t1);             // v_min3
            }
            colLds[threadIdx.x][j]     = colA;   // adjacent -> b64 write
            colLds[threadIdx.x][j + 1] = colB;
        }
        __syncthreads();

        // Col tree: 4 row-groups of 32 threads, one (rowgroup, target)/thread.
        {
            const int rg = threadIdx.x >> 5;   // 0..3
            const int t  = threadIdx.x & 31;   // target within group
            float cp = 3.4e38f;
#pragma unroll
            for (int i = 0; i < 32; ++i)
                cp = fminf(cp, colLds[rg * 32 + i][t]);
            cmPart[rg][t] = cp;
        }
        __syncthreads();
        if (threadIdx.x < GRP) {
            const int t = threadIdx.x;
            float cm = fminf(fminf(cmPart[0][t], cmPart[1][t]),
                             fminf(cmPart[2][t], cmPart[3][t]));
            colmin[(size_t)b * NPTS + chunk * TC + g * GRP + t] = cm;
        }
        __syncthreads();
    }

    // Row partials: plain coalesced writes — no init, no atomics.
    float* pbase = part + ((size_t)b * TCH + chunk) * NPTS;
#pragma unroll
    for (int k = 0; k < QPT; ++k)
        pbase[threadIdx.x + k * THREADS] = mn[k];
}

#define CTHREADS 256

__global__ __launch_bounds__(CTHREADS) void chamfer_combine(
    const float* __restrict__ part,
    const float* __restrict__ colmin,
    float* __restrict__ blocksums /* [NROWB + NCOLB] */)
{
    __shared__ float wsum[CTHREADS / 64];

    const int blk = blockIdx.x;        // 288 = NROWB + NCOLB
    float d;

    if (blk < NROWB) {
        // Row: min over 32 chunks for one query, d = 2c.
        const int b  = blk >> 3;
        const int qc = blk & 7;
        const int qi = qc * CTHREADS + threadIdx.x;
        const float* p = part + (size_t)b * TCH * NPTS + qi;
        float mn = p[0];
#pragma unroll
        for (int c = 1; c < TCH; ++c)
            mn = fminf(mn, p[(size_t)c * NPTS]);
        d = 2.0f * mn;
    } else {
        // Col: sum 2*colmin over this batch (8 values per thread).
        const int b = blk - NROWB;
        const float* p = colmin + (size_t)b * NPTS;
        float s = 0.0f;
#pragma unroll
        for (int i = 0; i < 8; ++i)
            s += p[threadIdx.x + i * CTHREADS];
        d = 2.0f * s;
    }

    for (int off = 32; off > 0; off >>= 1)
        d += __shfl_down(d, off);
    if ((threadIdx.x & 63) == 0) wsum[threadIdx.x >> 6] = d;
    __syncthreads();
    if (threadIdx.x == 0)
        blocksums[blk] = wsum[0] + wsum[1] + wsum[2] + wsum[3];
}

__global__ void chamfer_finalize(const float* __restrict__ blocksums,
                                 float* __restrict__ out)
{
    const int lane = threadIdx.x;   // 64 threads; lanes >= 32 contribute 0
    float v = 0.0f;
    if (lane < BATCH) {
        float rs = 0.0f;
#pragma unroll
        for (int i = 0; i < 8; ++i)
            rs += blocksums[lane * 8 + i];
        float cs = blocksums[NROWB + lane];
        v = fmaxf(rs, cs) * (1.0f / NPTS);
    }
    for (int off = 32; off > 0; off >>= 1)
        v += __shfl_down(v, off);
    if (lane == 0) out[0] = v * (1.0f / BATCH);
}

extern "C" void kernel_launch(void* const* d_in, const int* in_sizes, int n_in,
                              void* d_out, int out_size, void* d_ws, size_t ws_size,
                              hipStream_t stream) {
    const float* x = (const float*)d_in[0];
    const float* y = (const float*)d_in[1];
    float* out = (float*)d_out;

    float* part      = (float*)d_ws;                          // 8 MB
    float* colmin    = part + (size_t)BATCH * TCH * NPTS;     // 256 KB
    float* blocksums = colmin + (size_t)BATCH * NPTS;         // ~1.2 KB

    chamfer_min<<<BATCH * TCH, THREADS, 0, stream>>>(x, y, part, colmin);
    chamfer_combine<<<NROWB + NCOLB, CTHREADS, 0, stream>>>(part, colmin, blocksums);
    chamfer_finalize<<<1, 64, 0, stream>>>(blocksums, out);
}